// Round 5
// baseline (206.889 us; speedup 1.0000x reference)
//
#include <hip/hip_runtime.h>
#include <hip/hip_bf16.h>

#define NB 8
#define NC 128
#define NT 4096
#define NS 1024

typedef short bf16x8 __attribute__((ext_vector_type(8)));
typedef float f32x4  __attribute__((ext_vector_type(4)));

#define MFMA16(a, b, c) __builtin_amdgcn_mfma_f32_16x16x32_bf16(a, b, c, 0, 0, 0)

__device__ __forceinline__ short f2b(float x) {
    __hip_bfloat16 h = __float2bfloat16(x);
    return *reinterpret_cast<short*>(&h);
}

// async global->LDS, 16B per lane; dest = wave-uniform base + lane*16 (linear)
__device__ __forceinline__ void gl_lds16(const void* g, void* l) {
    __builtin_amdgcn_global_load_lds(
        (const __attribute__((address_space(1))) unsigned int*)g,
        (__attribute__((address_space(3))) unsigned int*)l, 16, 0, 0);
}

// ---------------------------------------------------------------------------
// Pack complex weights into doubled-K (256) bf16 matrices, row = out col d',
// col = k.  Q/K: [256][256]: rows<128 (real out): [Wr | -Wi]; rows>=128 (imag
// out): [Wi | Wr].  V (real out only): [128][256] = [Wvr | -Wvi].
// ---------------------------------------------------------------------------
__global__ __launch_bounds__(256) void pack_w_kernel(
    const float* __restrict__ Wqr, const float* __restrict__ Wqi,
    const float* __restrict__ Wkr, const float* __restrict__ Wki,
    const float* __restrict__ Wvr, const float* __restrict__ Wvi,
    __hip_bfloat16* __restrict__ WqT, __hip_bfloat16* __restrict__ WkT,
    __hip_bfloat16* __restrict__ WvT)
{
    const int idx = blockIdx.x * 256 + threadIdx.x;   // 640 blocks = 163840
    const float *Wr, *Wi; __hip_bfloat16* dst; int base;
    if (idx < 65536)       { Wr = Wqr; Wi = Wqi; dst = WqT; base = idx; }
    else if (idx < 131072) { Wr = Wkr; Wi = Wki; dst = WkT; base = idx - 65536; }
    else                   { Wr = Wvr; Wi = Wvi; dst = WvT; base = idx - 131072; }
    const int dp = base >> 8, k = base & 255;
    const int d  = dp & 127;
    float v;
    if (dp < 128) v = (k < 128) ? Wr[d * 128 + k] : -Wi[d * 128 + k - 128];
    else          v = (k < 128) ? Wi[d * 128 + k] :  Wr[d * 128 + k - 128];
    dst[base] = __float2bfloat16(v);
}

// ---------------------------------------------------------------------------
// Merged K + V projection.  32-source-row tiles -> 256 blocks.
// ---------------------------------------------------------------------------
__global__ __launch_bounds__(256) void projKV_kernel(
    const float* __restrict__ Xr, const float* __restrict__ Xi,
    const __hip_bfloat16* __restrict__ WkT, const __hip_bfloat16* __restrict__ WvT,
    const float* __restrict__ bkr, const float* __restrict__ bki,
    const float* __restrict__ bvr,
    __hip_bfloat16* __restrict__ Kh, __hip_bfloat16* __restrict__ VrT)
{
    __shared__ __align__(16) char smem[27136];   // As[32][528] + Vstash[128][80]
    const int b   = blockIdx.x & 7;              // batch -> XCD affinity
    const int n0  = (blockIdx.x >> 3) * 32;
    const int tid = threadIdx.x;

    for (int i = tid; i < 32 * 64; i += 256) {
        const int cp = i >> 5, n = i & 31, c = cp * 2;
        const size_t rb = (size_t)(b * NC + c) * NS + n0 + n;
        const unsigned pr = (unsigned short)f2b(Xr[rb]) |
                            ((unsigned)(unsigned short)f2b(Xr[rb + NS]) << 16);
        const unsigned pi = (unsigned short)f2b(Xi[rb]) |
                            ((unsigned)(unsigned short)f2b(Xi[rb + NS]) << 16);
        *(unsigned*)(smem + n * 528 + c * 2)         = pr;
        *(unsigned*)(smem + n * 528 + (128 + c) * 2) = pi;
    }
    __syncthreads();

    const int w = tid >> 6, l15 = tid & 15, q = (tid & 63) >> 4;
    const int r0 = (w & 1) * 16;                 // rows within 32-row tile
    const int g  = w >> 1;                       // column group

    const char* wp[12];
    #pragma unroll
    for (int jj = 0; jj < 12; ++jj) {
        const int j = g * 12 + jj;               // global col tile 0..23
        wp[jj] = (j < 16)
            ? (const char*)WkT + (size_t)(j * 16 + l15) * 512 + q * 16
            : (const char*)WvT + (size_t)((j - 16) * 16 + l15) * 512 + q * 16;
    }

    f32x4 acc[12];
    #pragma unroll
    for (int jj = 0; jj < 12; ++jj) { acc[jj][0]=0.f; acc[jj][1]=0.f; acc[jj][2]=0.f; acc[jj][3]=0.f; }

    #pragma unroll
    for (int t = 0; t < 8; ++t) {
        const bf16x8 af = *(const bf16x8*)(smem + (r0 + l15) * 528 + (t * 32 + q * 8) * 2);
        #pragma unroll
        for (int jj = 0; jj < 12; ++jj) {
            const bf16x8 bf = *(const bf16x8*)(wp[jj] + t * 64);
            acc[jj] = MFMA16(af, bf, acc[jj]);
        }
    }

    #pragma unroll
    for (int jj = 0; jj < 12; ++jj) {
        const int j = g * 12 + jj;
        if (j < 16) {                            // K epilogue: direct global
            const int col = j * 16 + l15;
            const float bv = (col < 128) ? bkr[col] : bki[col - 128];
            #pragma unroll
            for (int r = 0; r < 4; ++r) {
                const int n = n0 + r0 + q * 4 + r;
                Kh[((size_t)(b * NS + n) << 8) + col] = __float2bfloat16(acc[jj][r] + bv);
            }
        } else {                                 // V epilogue: LDS transpose stash
            const int d = (j - 16) * 16 + l15;
            #pragma unroll
            for (int r = 0; r < 4; ++r)
                *(__hip_bfloat16*)(smem + 16896 + d * 80 + (r0 + q * 4 + r) * 2) =
                    __float2bfloat16(acc[jj][r] + bvr[d]);
        }
    }
    __syncthreads();
    for (int i = tid; i < 128 * 4; i += 256) {
        const int d = i >> 2, seg = i & 3;
        const int4 v = *(const int4*)(smem + 16896 + d * 80 + seg * 16);
        *(int4*)((char*)VrT + ((size_t)(b * NC + d) * NS + n0) * 2 + seg * 16) = v;
    }
}

// ---------------------------------------------------------------------------
// Stage one 32-source-row chunk (K 16KB + V 8KB) into LDS buffer `buf`.
// K rows swizzled: LDS slot s of row ml holds global slot s ^ (ml&7).
// V rows swizzled: LDS slot s of row d holds global slot s ^ (d&3).
// All via global_load_lds (linear dest, pre-swizzled source; rule 21).
// ---------------------------------------------------------------------------
__device__ __forceinline__ void stage_chunk(const char* Kbase, const char* Vbase,
                                            char* buf, int ch, int w, int lane)
{
    const char* ks = Kbase + (size_t)ch * 16384;
    #pragma unroll
    for (int i = 0; i < 4; ++i) {
        const int ml = w * 8 + i * 2 + (lane >> 5);          // K row 0..31
        const int so = ml * 512 + (((lane & 31) ^ (ml & 7)) << 4);
        gl_lds16(ks + so, buf + (w * 4 + i) * 1024);
    }
    const char* vsrc = Vbase + (size_t)ch * 64;
    #pragma unroll
    for (int i = 0; i < 2; ++i) {
        const int d  = (w + i * 4) * 16 + (lane >> 2);       // V row 0..127
        const int so = d * 2048 + (((lane & 3) ^ ((lane >> 2) & 3)) << 4);
        gl_lds16(vsrc + so, buf + 16384 + (w + i * 4) * 1024);
    }
}

// ---------------------------------------------------------------------------
// Flash attention, inline Q projection.  Block = batch b x 128 target rows,
// 4 waves x 32 rows each (2 x 16-row MFMA tiles) -> every K/V LDS fragment
// read feeds TWO row-tiles, halving LDS/L2 K,V traffic per unit of work.
// No-max softmax: p = exp2(S'), denominator via ones-column MFMA.
// 4 chunk buffers; plain __syncthreads() every 2 chunks (pending stages are
// a full iteration old -> the implicit vmcnt(0) drain is free); chunks c+2,
// c+3 staged right after the barrier.
// ---------------------------------------------------------------------------
__global__ __launch_bounds__(256, 1) void attn_mfma_kernel(
    const float* __restrict__ tr_g, const float* __restrict__ ti_g,
    const __hip_bfloat16* __restrict__ WqT,
    const float* __restrict__ bqr, const float* __restrict__ bqi,
    const __hip_bfloat16* __restrict__ Kh, const __hip_bfloat16* __restrict__ VrT,
    const float* __restrict__ gamma_p, float* __restrict__ out)
{
    __shared__ __align__(16) char smem[108544];
    // [0, 98304): 4 x 24576 chunk buffers (K 16KB + V 8KB each).
    // Prologue overlays As[128][528] = 67584 B; epilogue overlays Of.
    // [98304, 108544): P, 4 waves x 2560 B (2 row-tiles x 1280), wave-private.
    char* As = smem;
    char* ps = smem + 98304;

    const int b    = blockIdx.x & 7;             // batch -> XCD affinity
    const int n0   = (blockIdx.x >> 3) * 128;
    const int tid  = threadIdx.x;
    const int w    = tid >> 6, lane = tid & 63, l15 = tid & 15, q = (tid & 63) >> 4;
    const int row0 = w * 32;
    char* psw = ps + w * 2560;

    // ---- stage target tile As[n][c] (128 x 256 bf16, pitch 528) ----
    for (int i = tid; i < 128 * 64; i += 256) {
        const int cp = i >> 7, n = i & 127, c = cp * 2;
        const size_t rb = (size_t)(b * NC + c) * NT + n0 + n;
        const unsigned pr = (unsigned short)f2b(tr_g[rb]) |
                            ((unsigned)(unsigned short)f2b(tr_g[rb + NT]) << 16);
        const unsigned pi = (unsigned short)f2b(ti_g[rb]) |
                            ((unsigned)(unsigned short)f2b(ti_g[rb + NT]) << 16);
        *(unsigned*)(As + n * 528 + c * 2)         = pr;
        *(unsigned*)(As + n * 528 + (128 + c) * 2) = pi;
    }
    __syncthreads();

    // ---- inline Q projection, 2 row-tiles per wave (wave-private rows) ----
    bf16x8 qf[2][8];
    const float inv_s = 0.12751744f;             // log2(e) / sqrt(128)
    #pragma unroll
    for (int rt = 0; rt < 2; ++rt) {
        const int rbase = row0 + rt * 16;
        f32x4 qacc[16];
        #pragma unroll
        for (int j = 0; j < 16; ++j) { qacc[j][0]=0.f; qacc[j][1]=0.f; qacc[j][2]=0.f; qacc[j][3]=0.f; }
        #pragma unroll
        for (int t = 0; t < 8; ++t) {
            const bf16x8 af = *(const bf16x8*)(As + (rbase + l15) * 528 + (t * 32 + q * 8) * 2);
            #pragma unroll
            for (int j = 0; j < 16; ++j) {
                const int col = j * 16 + l15;
                const bf16x8 bf = *(const bf16x8*)((const char*)WqT + col * 512 + (t * 32 + q * 8) * 2);
                qacc[j] = MFMA16(af, bf, qacc[j]);
            }
        }
        #pragma unroll
        for (int j = 0; j < 16; ++j) {
            const int col  = j * 16 + l15;
            const float bv = (col < 128) ? bqr[col] : bqi[col - 128];
            #pragma unroll
            for (int r = 0; r < 4; ++r) {
                const int row = rbase + q * 4 + r;
                *(__hip_bfloat16*)(As + row * 528 + col * 2) =
                    __float2bfloat16((qacc[j][r] + bv) * inv_s);
            }
        }
        #pragma unroll
        for (int t = 0; t < 8; ++t)
            qf[rt][t] = *(const bf16x8*)(As + (rbase + l15) * 528 + (t * 32 + q * 8) * 2);
    }
    __syncthreads();        // all waves hold qf; As region free for buffers

    const char* Kbase = (const char*)Kh + ((size_t)(b * NS) << 9);
    const char* Vbase = (const char*)VrT + (size_t)b * NC * NS * 2;

    stage_chunk(Kbase, Vbase, smem,         0, w, lane);
    stage_chunk(Kbase, Vbase, smem + 24576, 1, w, lane);

    f32x4 oacc[2][8];
    #pragma unroll
    for (int rt = 0; rt < 2; ++rt)
        #pragma unroll
        for (int j = 0; j < 8; ++j) { oacc[rt][j][0]=0.f; oacc[rt][j][1]=0.f; oacc[rt][j][2]=0.f; oacc[rt][j][3]=0.f; }
    f32x4 lacc[2];
    lacc[0][0]=0.f; lacc[0][1]=0.f; lacc[0][2]=0.f; lacc[0][3]=0.f;
    lacc[1][0]=0.f; lacc[1][1]=0.f; lacc[1][2]=0.f; lacc[1][3]=0.f;

    // B-fragment of the all-ones column: B col 0 (lanes l15==0) = 1.0bf16
    bf16x8 onesf;
    {
        const short ob = (l15 == 0) ? (short)0x3F80 : (short)0;
        #pragma unroll
        for (int e = 0; e < 8; ++e) onesf[e] = ob;
    }

    // swizzled read-offset components
    const int e3   = l15 & 7;
    const int qx   = q ^ (e3 & 3);           // K slot low bits
    const int eh   = e3 >> 2;                // K slot high bit
    const int vswz = (q ^ (l15 & 3)) << 4;   // V slot

    #pragma unroll 1
    for (int it = 0; it < 16; ++it) {
        const int c0 = it * 2;
        // implicit vmcnt(0)+lgkmcnt(0) drain is free: pending stages were
        // issued a full 2-chunk iteration (~2000 cy) ago.
        __syncthreads();
        if (c0 + 2 < 32) {
            stage_chunk(Kbase, Vbase, smem + ((c0 + 2) & 3) * 24576, c0 + 2, w, lane);
            stage_chunk(Kbase, Vbase, smem + ((c0 + 3) & 3) * 24576, c0 + 3, w, lane);
        }

        #pragma unroll
        for (int cc = 0; cc < 2; ++cc) {
            char* bA = smem + ((c0 + cc) & 3) * 24576;

            // ---- QK^T: each kf read feeds both row-tiles ----
            f32x4 s00, s01, s10, s11;
            s00[0]=0.f; s00[1]=0.f; s00[2]=0.f; s00[3]=0.f;
            s01[0]=0.f; s01[1]=0.f; s01[2]=0.f; s01[3]=0.f;
            s10[0]=0.f; s10[1]=0.f; s10[2]=0.f; s10[3]=0.f;
            s11[0]=0.f; s11[1]=0.f; s11[2]=0.f; s11[3]=0.f;
            #pragma unroll
            for (int t = 0; t < 8; ++t) {
                const int tb = ((t ^ eh) << 6) + (qx << 4);
                const bf16x8 k0 = *(const bf16x8*)(bA + l15 * 512 + tb);
                s00 = MFMA16(qf[0][t], k0, s00);
                s10 = MFMA16(qf[1][t], k0, s10);
                const bf16x8 k1 = *(const bf16x8*)(bA + (16 + l15) * 512 + tb);
                s01 = MFMA16(qf[0][t], k1, s01);
                s11 = MFMA16(qf[1][t], k1, s11);
            }

            // ---- p = 2^S' directly; P -> wave-private LDS ----
            #pragma unroll
            for (int r = 0; r < 4; ++r) {
                *(__hip_bfloat16*)(psw + (q * 4 + r) * 80 + l15 * 2) =
                    __float2bfloat16(exp2f(s00[r]));
                *(__hip_bfloat16*)(psw + (q * 4 + r) * 80 + (16 + l15) * 2) =
                    __float2bfloat16(exp2f(s01[r]));
                *(__hip_bfloat16*)(psw + 1280 + (q * 4 + r) * 80 + l15 * 2) =
                    __float2bfloat16(exp2f(s10[r]));
                *(__hip_bfloat16*)(psw + 1280 + (q * 4 + r) * 80 + (16 + l15) * 2) =
                    __float2bfloat16(exp2f(s11[r]));
            }

            // ---- V fragments once per chunk, shared by both row-tiles ----
            bf16x8 vfr[8];
            #pragma unroll
            for (int j = 0; j < 8; ++j)
                vfr[j] = *(const bf16x8*)(bA + 16384 + (j * 16 + l15) * 64 + vswz);

            // ---- PV + ones-column denominator ----
            #pragma unroll
            for (int rt = 0; rt < 2; ++rt) {
                const bf16x8 pf = *(const bf16x8*)(psw + rt * 1280 + l15 * 80 + q * 16);
                lacc[rt] = MFMA16(pf, onesf, lacc[rt]);
                #pragma unroll
                for (int j = 0; j < 8; ++j)
                    oacc[rt][j] = MFMA16(pf, vfr[j], oacc[rt][j]);
            }
        }
    }

    // ---- epilogue ----
    __syncthreads();                         // drains nothing new; reuse smem
    float* Of = (float*)smem;                // 128 d x 132 m f32 = 67584 B
    const float g = gamma_p[0];
    #pragma unroll
    for (int rt = 0; rt < 2; ++rt) {
        #pragma unroll
        for (int r = 0; r < 4; ++r) {
            const float lr = __shfl(lacc[rt][r], q * 16, 64);
            const float inv_l = g / fmaxf(lr, 1e-30f);
            const int m = row0 + rt * 16 + q * 4 + r;
            #pragma unroll
            for (int j = 0; j < 8; ++j)
                Of[(j * 16 + l15) * 132 + m] = oacc[rt][j][r] * inv_l;
        }
    }
    __syncthreads();
    float* ob = out + (size_t)b * NC * NT + n0;
    for (int i = tid; i < 128 * 32; i += 256) {
        const int d = i >> 5, ms = (i & 31) * 4;
        const float4 v = *(const float4*)&Of[d * 132 + ms];
        *(float4*)(ob + (size_t)d * NT + ms) = v;
    }
}

// ---------------------------------------------------------------------------
extern "C" void kernel_launch(void* const* d_in, const int* in_sizes, int n_in,
                              void* d_out, int out_size, void* d_ws, size_t ws_size,
                              hipStream_t stream)
{
    const float* target_r = (const float*)d_in[0];
    const float* target_i = (const float*)d_in[1];
    const float* source_r = (const float*)d_in[2];
    const float* source_i = (const float*)d_in[3];
    const float* Wq_r = (const float*)d_in[4];
    const float* Wq_i = (const float*)d_in[5];
    const float* bq_r = (const float*)d_in[6];
    const float* bq_i = (const float*)d_in[7];
    const float* Wk_r = (const float*)d_in[8];
    const float* Wk_i = (const float*)d_in[9];
    const float* bk_r = (const float*)d_in[10];
    const float* bk_i = (const float*)d_in[11];
    const float* Wv_r = (const float*)d_in[12];
    const float* Wv_i = (const float*)d_in[13];
    const float* bv_r = (const float*)d_in[14];
    const float* bv_i = (const float*)d_in[15];
    const float* gamma = (const float*)d_in[16];

    // workspace carve (bytes) — total 6.62 MB
    char* ws = (char*)d_ws;
    __hip_bfloat16* Kh  = (__hip_bfloat16*)(ws);                    // 4,194,304
    __hip_bfloat16* VrT = (__hip_bfloat16*)(ws + 4194304);          // 2,097,152
    __hip_bfloat16* WqT = (__hip_bfloat16*)(ws + 6291456);          //   131,072
    __hip_bfloat16* WkT = (__hip_bfloat16*)(ws + 6422528);          //   131,072
    __hip_bfloat16* WvT = (__hip_bfloat16*)(ws + 6553600);          //    65,536

    pack_w_kernel<<<640, 256, 0, stream>>>(Wq_r, Wq_i, Wk_r, Wk_i, Wv_r, Wv_i,
                                           WqT, WkT, WvT);

    projKV_kernel<<<NB * (NS / 32), 256, 0, stream>>>(
        source_r, source_i, WkT, WvT, bk_r, bk_i, bv_r, Kh, VrT);

    attn_mfma_kernel<<<NB * (NT / 128), 256, 0, stream>>>(
        target_r, target_i, WqT, bq_r, bq_i, Kh, VrT, gamma, (float*)d_out);
}

// Round 6
// 190.554 us; speedup vs baseline: 1.0857x; 1.0857x over previous
//
#include <hip/hip_runtime.h>
#include <hip/hip_bf16.h>

#define NB 8
#define NC 128
#define NT 4096
#define NS 1024

typedef short bf16x8 __attribute__((ext_vector_type(8)));
typedef float f32x4  __attribute__((ext_vector_type(4)));

#define MFMA16(a, b, c) __builtin_amdgcn_mfma_f32_16x16x32_bf16(a, b, c, 0, 0, 0)

__device__ __forceinline__ short f2b(float x) {
    __hip_bfloat16 h = __float2bfloat16(x);
    return *reinterpret_cast<short*>(&h);
}

// async global->LDS, 16B per lane; dest = wave-uniform base + lane*16 (linear)
__device__ __forceinline__ void gl_lds16(const void* g, void* l) {
    __builtin_amdgcn_global_load_lds(
        (const __attribute__((address_space(1))) unsigned int*)g,
        (__attribute__((address_space(3))) unsigned int*)l, 16, 0, 0);
}

// ---------------------------------------------------------------------------
// Pack complex weights into doubled-K (256) bf16 matrices, row = out col d',
// col = k.  Q/K: [256][256]: rows<128 (real out): [Wr | -Wi]; rows>=128 (imag
// out): [Wi | Wr].  V (real out only): [128][256] = [Wvr | -Wvi].
// ---------------------------------------------------------------------------
__global__ __launch_bounds__(256) void pack_w_kernel(
    const float* __restrict__ Wqr, const float* __restrict__ Wqi,
    const float* __restrict__ Wkr, const float* __restrict__ Wki,
    const float* __restrict__ Wvr, const float* __restrict__ Wvi,
    __hip_bfloat16* __restrict__ WqT, __hip_bfloat16* __restrict__ WkT,
    __hip_bfloat16* __restrict__ WvT)
{
    const int idx = blockIdx.x * 256 + threadIdx.x;   // 640 blocks = 163840
    const float *Wr, *Wi; __hip_bfloat16* dst; int base;
    if (idx < 65536)       { Wr = Wqr; Wi = Wqi; dst = WqT; base = idx; }
    else if (idx < 131072) { Wr = Wkr; Wi = Wki; dst = WkT; base = idx - 65536; }
    else                   { Wr = Wvr; Wi = Wvi; dst = WvT; base = idx - 131072; }
    const int dp = base >> 8, k = base & 255;
    const int d  = dp & 127;
    float v;
    if (dp < 128) v = (k < 128) ? Wr[d * 128 + k] : -Wi[d * 128 + k - 128];
    else          v = (k < 128) ? Wi[d * 128 + k] :  Wr[d * 128 + k - 128];
    dst[base] = __float2bfloat16(v);
}

// ---------------------------------------------------------------------------
// Merged K + V projection.  16-source-row tiles -> 512 blocks (2 blocks/CU).
// 4 waves each own 6 output col-tiles (24 total = 256 K cols + 128 V cols).
// ---------------------------------------------------------------------------
__global__ __launch_bounds__(256) void projKV_kernel(
    const float* __restrict__ Xr, const float* __restrict__ Xi,
    const __hip_bfloat16* __restrict__ WkT, const __hip_bfloat16* __restrict__ WvT,
    const float* __restrict__ bkr, const float* __restrict__ bki,
    const float* __restrict__ bvr,
    __hip_bfloat16* __restrict__ Kh, __hip_bfloat16* __restrict__ VrT)
{
    __shared__ __align__(16) char smem[13568];   // As[16][528] + Vstash[128][40]
    const int b   = blockIdx.x & 7;              // batch -> XCD affinity
    const int n0  = (blockIdx.x >> 3) * 16;
    const int tid = threadIdx.x;

    for (int i = tid; i < 16 * 64; i += 256) {
        const int cp = i >> 4, n = i & 15, c = cp * 2;
        const size_t rb = (size_t)(b * NC + c) * NS + n0 + n;
        const unsigned pr = (unsigned short)f2b(Xr[rb]) |
                            ((unsigned)(unsigned short)f2b(Xr[rb + NS]) << 16);
        const unsigned pi = (unsigned short)f2b(Xi[rb]) |
                            ((unsigned)(unsigned short)f2b(Xi[rb + NS]) << 16);
        *(unsigned*)(smem + n * 528 + c * 2)         = pr;
        *(unsigned*)(smem + n * 528 + (128 + c) * 2) = pi;
    }
    __syncthreads();

    const int w = tid >> 6, l15 = tid & 15, q = (tid & 63) >> 4;

    const char* wp[6];
    #pragma unroll
    for (int jj = 0; jj < 6; ++jj) {
        const int j = w * 6 + jj;                // global col tile 0..23
        wp[jj] = (j < 16)
            ? (const char*)WkT + (size_t)(j * 16 + l15) * 512 + q * 16
            : (const char*)WvT + (size_t)((j - 16) * 16 + l15) * 512 + q * 16;
    }

    f32x4 acc[6];
    #pragma unroll
    for (int jj = 0; jj < 6; ++jj) { acc[jj][0]=0.f; acc[jj][1]=0.f; acc[jj][2]=0.f; acc[jj][3]=0.f; }

    #pragma unroll
    for (int t = 0; t < 8; ++t) {
        const bf16x8 af = *(const bf16x8*)(smem + l15 * 528 + (t * 32 + q * 8) * 2);
        #pragma unroll
        for (int jj = 0; jj < 6; ++jj) {
            const bf16x8 bf = *(const bf16x8*)(wp[jj] + t * 64);
            acc[jj] = MFMA16(af, bf, acc[jj]);
        }
    }

    #pragma unroll
    for (int jj = 0; jj < 6; ++jj) {
        const int j = w * 6 + jj;
        if (j < 16) {                            // K epilogue: direct global
            const int col = j * 16 + l15;
            const float bv = (col < 128) ? bkr[col] : bki[col - 128];
            #pragma unroll
            for (int r = 0; r < 4; ++r) {
                const int n = n0 + q * 4 + r;
                Kh[((size_t)(b * NS + n) << 8) + col] = __float2bfloat16(acc[jj][r] + bv);
            }
        } else {                                 // V epilogue: LDS transpose stash
            const int d = (j - 16) * 16 + l15;
            #pragma unroll
            for (int r = 0; r < 4; ++r)
                *(__hip_bfloat16*)(smem + 8448 + d * 40 + (q * 4 + r) * 2) =
                    __float2bfloat16(acc[jj][r] + bvr[d]);
        }
    }
    __syncthreads();
    for (int i = tid; i < 128 * 2; i += 256) {
        const int d = i >> 1, seg = i & 1;
        const int4 v = *(const int4*)(smem + 8448 + d * 40 + seg * 16);
        *(int4*)((char*)VrT + ((size_t)(b * NC + d) * NS + n0) * 2 + seg * 16) = v;
    }
}

// ---------------------------------------------------------------------------
// Stage one 32-source-row chunk (K 16KB + V 8KB) into LDS buffer `buf`.
// K rows are sigma-PERMUTED at stage time: LDS row j holds global k-row
//   G(j) = ((j>>2)&3)*8 + (j>>4)*4 + (j&3)
// (tile0 = k rows {0-3,8-11,16-19,24-27}, tile1 = complement) so that after
// the swapped QK^T each lane's S registers are k = q*8..q*8+7 — the exact
// PV A-fragment slice (P never goes through LDS).
// K slots swizzled: LDS slot s of LDS-row j holds global slot s ^ (j&7).
// V rows swizzled: LDS slot s of row d holds global slot s ^ (d&3).
// ---------------------------------------------------------------------------
__device__ __forceinline__ void stage_chunk(const char* Kbase, const char* Vbase,
                                            char* buf, int ch, int w, int lane)
{
    const char* ks = Kbase + (size_t)ch * 16384;
    #pragma unroll
    for (int i = 0; i < 4; ++i) {
        const int ml = w * 8 + i * 2 + (lane >> 5);          // LDS K row 0..31
        const int gr = ((ml >> 2) & 3) * 8 + ((ml >> 4) << 2) + (ml & 3);
        const int so = gr * 512 + (((lane & 31) ^ (ml & 7)) << 4);
        gl_lds16(ks + so, buf + (w * 4 + i) * 1024);
    }
    const char* vsrc = Vbase + (size_t)ch * 64;
    #pragma unroll
    for (int i = 0; i < 2; ++i) {
        const int d  = (w + i * 4) * 16 + (lane >> 2);       // V row 0..127
        const int so = d * 2048 + (((lane & 3) ^ ((lane >> 2) & 3)) << 4);
        gl_lds16(vsrc + so, buf + 16384 + (w + i * 4) * 1024);
    }
}

// ---------------------------------------------------------------------------
// Flash attention, inline Q projection.  Block = batch b x 64 target rows,
// 4 waves x 16 rows.  SWAPPED QK^T (mfma(K,Q)) + sigma-permuted K staging
// makes P fully lane-local: p = exp2(S') in regs, packed to bf16, fed
// straight into PV and the ones-column denominator MFMA — no P LDS
// roundtrip, no cross-lane ops, no mid-chunk lgkm wait.
// K+V triple-buffered, staged 2 ahead via global_load_lds; counted
// s_waitcnt vmcnt(6) + raw s_barrier per chunk (never drained to 0).
// ---------------------------------------------------------------------------
__global__ __launch_bounds__(256, 2) void attn_mfma_kernel(
    const float* __restrict__ tr_g, const float* __restrict__ ti_g,
    const __hip_bfloat16* __restrict__ WqT,
    const float* __restrict__ bqr, const float* __restrict__ bqi,
    const __hip_bfloat16* __restrict__ Kh, const __hip_bfloat16* __restrict__ VrT,
    const float* __restrict__ gamma_p, float* __restrict__ out)
{
    __shared__ __align__(16) char smem[73728];
    // [0, 73728): 3 x 24576 chunk buffers (K 16KB + V 8KB each).
    // Prologue overlays As[64][528] = 33792 B on the same region.
    char* As = smem;

    const int b    = blockIdx.x & 7;             // batch -> XCD affinity
    const int n0   = (blockIdx.x >> 3) * 64;
    const int tid  = threadIdx.x;
    const int w    = tid >> 6, lane = tid & 63, l15 = tid & 15, q = (tid & 63) >> 4;
    const int row0 = w * 16;

    // ---- stage target tile As[n][c] (64 x 256 bf16) ----
    for (int i = tid; i < 64 * 64; i += 256) {
        const int cp = i >> 6, n = i & 63, c = cp * 2;
        const size_t rb = (size_t)(b * NC + c) * NT + n0 + n;
        const unsigned pr = (unsigned short)f2b(tr_g[rb]) |
                            ((unsigned)(unsigned short)f2b(tr_g[rb + NT]) << 16);
        const unsigned pi = (unsigned short)f2b(ti_g[rb]) |
                            ((unsigned)(unsigned short)f2b(ti_g[rb + NT]) << 16);
        *(unsigned*)(As + n * 528 + c * 2)         = pr;
        *(unsigned*)(As + n * 528 + (128 + c) * 2) = pi;
    }
    __syncthreads();

    // ---- inline Q projection (wave-private rows); scale = log2e/sqrt(C) ----
    bf16x8 qf[8];
    {
        f32x4 qacc[16];
        #pragma unroll
        for (int j = 0; j < 16; ++j) { qacc[j][0]=0.f; qacc[j][1]=0.f; qacc[j][2]=0.f; qacc[j][3]=0.f; }
        #pragma unroll
        for (int t = 0; t < 8; ++t) {
            const bf16x8 af = *(const bf16x8*)(As + (row0 + l15) * 528 + (t * 32 + q * 8) * 2);
            #pragma unroll
            for (int j = 0; j < 16; ++j) {
                const int col = j * 16 + l15;
                const bf16x8 bf = *(const bf16x8*)((const char*)WqT + col * 512 + (t * 32 + q * 8) * 2);
                qacc[j] = MFMA16(af, bf, qacc[j]);
            }
        }
        const float inv_s = 0.12751744f;         // log2(e) / sqrt(128)
        #pragma unroll
        for (int j = 0; j < 16; ++j) {
            const int col  = j * 16 + l15;
            const float bv = (col < 128) ? bqr[col] : bqi[col - 128];
            #pragma unroll
            for (int r = 0; r < 4; ++r) {
                const int row = row0 + q * 4 + r;
                *(__hip_bfloat16*)(As + row * 528 + col * 2) =
                    __float2bfloat16((qacc[j][r] + bv) * inv_s);
            }
        }
        #pragma unroll
        for (int t = 0; t < 8; ++t)
            qf[t] = *(const bf16x8*)(As + (row0 + l15) * 528 + (t * 32 + q * 8) * 2);
    }
    __syncthreads();        // all waves hold qf; As region free for buffers

    const char* Kbase = (const char*)Kh + ((size_t)(b * NS) << 9);
    const char* Vbase = (const char*)VrT + (size_t)b * NC * NS * 2;
    char* bA = smem;                 // current chunk
    char* bB = smem + 24576;         // chunk+1 (in flight)
    char* bC = smem + 49152;         // chunk+2 (staged this iter)

    stage_chunk(Kbase, Vbase, bA, 0, w, lane);   // 6 loads
    stage_chunk(Kbase, Vbase, bB, 1, w, lane);   // 12 outstanding

    f32x4 oacc[8];
    #pragma unroll
    for (int j = 0; j < 8; ++j) { oacc[j][0]=0.f; oacc[j][1]=0.f; oacc[j][2]=0.f; oacc[j][3]=0.f; }
    f32x4 lacc;                      // denominator: ones-column accumulator
    lacc[0]=0.f; lacc[1]=0.f; lacc[2]=0.f; lacc[3]=0.f;

    // B-fragment of the all-ones column: B col 0 (lanes l15==0) = 1.0bf16
    bf16x8 onesf;
    {
        const short ob = (l15 == 0) ? (short)0x3F80 : (short)0;
        #pragma unroll
        for (int e = 0; e < 8; ++e) onesf[e] = ob;
    }

    // swizzled read-offset components
    const int e3   = l15 & 7;
    const int qx   = q ^ (e3 & 3);           // K slot low bits
    const int eh   = e3 >> 2;                // K slot high bit
    const int vswz = (q ^ (l15 & 3)) << 4;   // V slot

    #pragma unroll 1
    for (int ch = 0; ch < 32; ++ch) {
        // retire exactly this chunk's 6 loads; chunk+1 stays in flight
        asm volatile("s_waitcnt vmcnt(6)" ::: "memory");
        __builtin_amdgcn_s_barrier();    // raw: no vmcnt(0) drain

        // stage chunk+2 (re-stage 31 on tail iters to keep vmcnt invariant)
        const int sch = (ch + 2 < 32) ? ch + 2 : 31;
        stage_chunk(Kbase, Vbase, bC, sch, w, lane);

        // ---- swapped QK^T: S = mfma(K', Q); lane holds S[k=q*8+e][qrow l15] ----
        f32x4 s0v, s1v;
        s0v[0]=0.f; s0v[1]=0.f; s0v[2]=0.f; s0v[3]=0.f;
        s1v[0]=0.f; s1v[1]=0.f; s1v[2]=0.f; s1v[3]=0.f;
        #pragma unroll
        for (int t = 0; t < 8; ++t) {
            const int tb = ((t ^ eh) << 6) + (qx << 4);
            const bf16x8 k0 = *(const bf16x8*)(bA + l15 * 512 + tb);
            s0v = MFMA16(k0, qf[t], s0v);            // tile0: k = q*8 + r
            const bf16x8 k1 = *(const bf16x8*)(bA + (16 + l15) * 512 + tb);
            s1v = MFMA16(k1, qf[t], s1v);            // tile1: k = q*8 + 4 + r
        }

        // ---- p = 2^S' in regs; pack to bf16 PA fragment (k = q*8..q*8+7) ----
        bf16x8 pa;
        #pragma unroll
        for (int r = 0; r < 4; ++r) {
            pa[r]     = f2b(exp2f(s0v[r]));
            pa[4 + r] = f2b(exp2f(s1v[r]));
        }

        // ---- PV + ones-column denominator, A-operand straight from regs ----
        lacc = MFMA16(pa, onesf, lacc);
        #pragma unroll
        for (int j = 0; j < 8; ++j) {
            const bf16x8 vf = *(const bf16x8*)(bA + 16384 + (j * 16 + l15) * 64 + vswz);
            oacc[j] = MFMA16(pa, vf, oacc[j]);
        }

        char* t0 = bA; bA = bB; bB = bC; bC = t0;   // rotate buffers
    }

    // ---- epilogue ----
    __syncthreads();                         // drains remaining staging
    float* Of = (float*)smem;                // 128 x 65 f32 (reuse buffers)
    const float g = gamma_p[0];
    #pragma unroll
    for (int r = 0; r < 4; ++r) {
        // l for my rows lives in lane (q*16) (l15==0 of my 16-lane group)
        const float lr = __shfl(lacc[r], q * 16, 64);
        const float inv_l = g / fmaxf(lr, 1e-30f);
        const int m = row0 + q * 4 + r;
        #pragma unroll
        for (int j = 0; j < 8; ++j)
            Of[(j * 16 + l15) * 65 + m] = oacc[j][r] * inv_l;
    }
    __syncthreads();
    float* ob = out + (size_t)b * NC * NT + n0;
    for (int i = tid; i < 128 * 64; i += 256) {
        const int d = i >> 6, m = i & 63;
        ob[(size_t)d * NT + m] = Of[d * 65 + m];
    }
}

// ---------------------------------------------------------------------------
extern "C" void kernel_launch(void* const* d_in, const int* in_sizes, int n_in,
                              void* d_out, int out_size, void* d_ws, size_t ws_size,
                              hipStream_t stream)
{
    const float* target_r = (const float*)d_in[0];
    const float* target_i = (const float*)d_in[1];
    const float* source_r = (const float*)d_in[2];
    const float* source_i = (const float*)d_in[3];
    const float* Wq_r = (const float*)d_in[4];
    const float* Wq_i = (const float*)d_in[5];
    const float* bq_r = (const float*)d_in[6];
    const float* bq_i = (const float*)d_in[7];
    const float* Wk_r = (const float*)d_in[8];
    const float* Wk_i = (const float*)d_in[9];
    const float* bk_r = (const float*)d_in[10];
    const float* bk_i = (const float*)d_in[11];
    const float* Wv_r = (const float*)d_in[12];
    const float* Wv_i = (const float*)d_in[13];
    const float* bv_r = (const float*)d_in[14];
    const float* bv_i = (const float*)d_in[15];
    const float* gamma = (const float*)d_in[16];

    // workspace carve (bytes) — total 6.62 MB
    char* ws = (char*)d_ws;
    __hip_bfloat16* Kh  = (__hip_bfloat16*)(ws);                    // 4,194,304
    __hip_bfloat16* VrT = (__hip_bfloat16*)(ws + 4194304);          // 2,097,152
    __hip_bfloat16* WqT = (__hip_bfloat16*)(ws + 6291456);          //   131,072
    __hip_bfloat16* WkT = (__hip_bfloat16*)(ws + 6422528);          //   131,072
    __hip_bfloat16* WvT = (__hip_bfloat16*)(ws + 6553600);          //    65,536

    pack_w_kernel<<<640, 256, 0, stream>>>(Wq_r, Wq_i, Wk_r, Wk_i, Wv_r, Wv_i,
                                           WqT, WkT, WvT);

    projKV_kernel<<<NB * (NS / 16), 256, 0, stream>>>(
        source_r, source_i, WkT, WvT, bk_r, bk_i, bv_r, Kh, VrT);

    attn_mfma_kernel<<<NB * (NT / 64), 256, 0, stream>>>(
        target_r, target_i, WqT, bq_r, bq_i, Kh, VrT, gamma, (float*)d_out);
}

// Round 7
// 186.639 us; speedup vs baseline: 1.1085x; 1.0210x over previous
//
#include <hip/hip_runtime.h>
#include <hip/hip_bf16.h>

#define NB 8
#define NC 128
#define NT 4096
#define NS 1024

typedef short bf16x8 __attribute__((ext_vector_type(8)));
typedef float f32x4  __attribute__((ext_vector_type(4)));
typedef float f32x16 __attribute__((ext_vector_type(16)));

#define MFMA16(a, b, c) __builtin_amdgcn_mfma_f32_16x16x32_bf16(a, b, c, 0, 0, 0)
#define MFMA32(a, b, c) __builtin_amdgcn_mfma_f32_32x32x16_bf16(a, b, c, 0, 0, 0)

__device__ __forceinline__ short f2b(float x) {
    __hip_bfloat16 h = __float2bfloat16(x);
    return *reinterpret_cast<short*>(&h);
}

__device__ __forceinline__ unsigned pk2(float a, float b) {
    return (unsigned)(unsigned short)f2b(a) | ((unsigned)(unsigned short)f2b(b) << 16);
}

// async global->LDS, 16B per lane; dest = wave-uniform base + lane*16 (linear)
__device__ __forceinline__ void gl_lds16(const void* g, void* l) {
    __builtin_amdgcn_global_load_lds(
        (const __attribute__((address_space(1))) unsigned int*)g,
        (__attribute__((address_space(3))) unsigned int*)l, 16, 0, 0);
}

// ---------------------------------------------------------------------------
// Pack complex weights into doubled-K (256) bf16 matrices, row = out col d',
// col = k.  Q/K: [256][256]: rows<128 (real out): [Wr | -Wi]; rows>=128 (imag
// out): [Wi | Wr].  V (real out only): [128][256] = [Wvr | -Wvi].
// ---------------------------------------------------------------------------
__global__ __launch_bounds__(256) void pack_w_kernel(
    const float* __restrict__ Wqr, const float* __restrict__ Wqi,
    const float* __restrict__ Wkr, const float* __restrict__ Wki,
    const float* __restrict__ Wvr, const float* __restrict__ Wvi,
    __hip_bfloat16* __restrict__ WqT, __hip_bfloat16* __restrict__ WkT,
    __hip_bfloat16* __restrict__ WvT)
{
    const int idx = blockIdx.x * 256 + threadIdx.x;   // 640 blocks = 163840
    const float *Wr, *Wi; __hip_bfloat16* dst; int base;
    if (idx < 65536)       { Wr = Wqr; Wi = Wqi; dst = WqT; base = idx; }
    else if (idx < 131072) { Wr = Wkr; Wi = Wki; dst = WkT; base = idx - 65536; }
    else                   { Wr = Wvr; Wi = Wvi; dst = WvT; base = idx - 131072; }
    const int dp = base >> 8, k = base & 255;
    const int d  = dp & 127;
    float v;
    if (dp < 128) v = (k < 128) ? Wr[d * 128 + k] : -Wi[d * 128 + k - 128];
    else          v = (k < 128) ? Wi[d * 128 + k] :  Wr[d * 128 + k - 128];
    dst[base] = __float2bfloat16(v);
}

// ---------------------------------------------------------------------------
// Merged K + V projection.  16-source-row tiles -> 512 blocks (2 blocks/CU).
// ---------------------------------------------------------------------------
__global__ __launch_bounds__(256) void projKV_kernel(
    const float* __restrict__ Xr, const float* __restrict__ Xi,
    const __hip_bfloat16* __restrict__ WkT, const __hip_bfloat16* __restrict__ WvT,
    const float* __restrict__ bkr, const float* __restrict__ bki,
    const float* __restrict__ bvr,
    __hip_bfloat16* __restrict__ Kh, __hip_bfloat16* __restrict__ VrT)
{
    __shared__ __align__(16) char smem[13568];   // As[16][528] + Vstash[128][40]
    const int b   = blockIdx.x & 7;              // batch -> XCD affinity
    const int n0  = (blockIdx.x >> 3) * 16;
    const int tid = threadIdx.x;

    for (int i = tid; i < 16 * 64; i += 256) {
        const int cp = i >> 4, n = i & 15, c = cp * 2;
        const size_t rb = (size_t)(b * NC + c) * NS + n0 + n;
        const unsigned pr = (unsigned short)f2b(Xr[rb]) |
                            ((unsigned)(unsigned short)f2b(Xr[rb + NS]) << 16);
        const unsigned pi = (unsigned short)f2b(Xi[rb]) |
                            ((unsigned)(unsigned short)f2b(Xi[rb + NS]) << 16);
        *(unsigned*)(smem + n * 528 + c * 2)         = pr;
        *(unsigned*)(smem + n * 528 + (128 + c) * 2) = pi;
    }
    __syncthreads();

    const int w = tid >> 6, l15 = tid & 15, q = (tid & 63) >> 4;

    const char* wp[6];
    #pragma unroll
    for (int jj = 0; jj < 6; ++jj) {
        const int j = w * 6 + jj;                // global col tile 0..23
        wp[jj] = (j < 16)
            ? (const char*)WkT + (size_t)(j * 16 + l15) * 512 + q * 16
            : (const char*)WvT + (size_t)((j - 16) * 16 + l15) * 512 + q * 16;
    }

    f32x4 acc[6];
    #pragma unroll
    for (int jj = 0; jj < 6; ++jj) { acc[jj][0]=0.f; acc[jj][1]=0.f; acc[jj][2]=0.f; acc[jj][3]=0.f; }

    #pragma unroll
    for (int t = 0; t < 8; ++t) {
        const bf16x8 af = *(const bf16x8*)(smem + l15 * 528 + (t * 32 + q * 8) * 2);
        #pragma unroll
        for (int jj = 0; jj < 6; ++jj) {
            const bf16x8 bf = *(const bf16x8*)(wp[jj] + t * 64);
            acc[jj] = MFMA16(af, bf, acc[jj]);
        }
    }

    #pragma unroll
    for (int jj = 0; jj < 6; ++jj) {
        const int j = w * 6 + jj;
        if (j < 16) {                            // K epilogue: direct global
            const int col = j * 16 + l15;
            const float bv = (col < 128) ? bkr[col] : bki[col - 128];
            #pragma unroll
            for (int r = 0; r < 4; ++r) {
                const int n = n0 + q * 4 + r;
                Kh[((size_t)(b * NS + n) << 8) + col] = __float2bfloat16(acc[jj][r] + bv);
            }
        } else {                                 // V epilogue: LDS transpose stash
            const int d = (j - 16) * 16 + l15;
            #pragma unroll
            for (int r = 0; r < 4; ++r)
                *(__hip_bfloat16*)(smem + 8448 + d * 40 + (q * 4 + r) * 2) =
                    __float2bfloat16(acc[jj][r] + bvr[d]);
        }
    }
    __syncthreads();
    for (int i = tid; i < 128 * 2; i += 256) {
        const int d = i >> 1, seg = i & 1;
        const int4 v = *(const int4*)(smem + 8448 + d * 40 + seg * 16);
        *(int4*)((char*)VrT + ((size_t)(b * NC + d) * NS + n0) * 2 + seg * 16) = v;
    }
}

// ---------------------------------------------------------------------------
// Stage one 32-source-row chunk (K 16KB + V 8KB) into LDS buffer `buf`.
// K rows identity; LDS slot s of K row r holds global slot s ^ (r&7).
// V rows: LDS slot s of row d holds global slot s ^ (d&3).
// All via global_load_lds (linear dest, pre-swizzled source; rule 21).
// ---------------------------------------------------------------------------
__device__ __forceinline__ void stage_chunk(const char* Kbase, const char* Vbase,
                                            char* buf, int ch, int w, int lane)
{
    const char* ks = Kbase + (size_t)ch * 16384;
    #pragma unroll
    for (int i = 0; i < 4; ++i) {
        const int ml = w * 8 + i * 2 + (lane >> 5);          // K row 0..31
        const int so = ml * 512 + (((lane & 31) ^ (ml & 7)) << 4);
        gl_lds16(ks + so, buf + (w * 4 + i) * 1024);
    }
    const char* vsrc = Vbase + (size_t)ch * 64;
    #pragma unroll
    for (int i = 0; i < 2; ++i) {
        const int d  = (w + i * 4) * 16 + (lane >> 2);       // V row 0..127
        const int so = d * 2048 + (((lane & 3) ^ ((lane >> 2) & 3)) << 4);
        gl_lds16(vsrc + so, buf + 16384 + (w + i * 4) * 1024);
    }
}

// ---------------------------------------------------------------------------
// Flash attention, 32x32 MFMA edition.  Block = batch b x 64 target rows.
// Waves 0,1 own q-halves 0-31/32-63 on EVEN chunks; waves 2,3 on ODD chunks
// (all 4 waves co-stage every chunk).  Each K/V fragment read now feeds 32
// q-rows -> half the LDS read traffic of the 16x16 version.
// Swapped QK^T (mfma32(K,Q)): S lane-local (col = l&31 = q); PV A-fragment
// assembled in-register via pack + shfl_xor(32) exchange.  No-max softmax;
// denominator via all-ones-B MFMA, reg-aligned with oacc.  Parity partials
// (pure sums) merged through LDS at the end.
// Cooperative Q-proj: wave w computes Q-hat cols 64w..64w+63 for ALL rows
// (reads only its quarter of WqT).  Triple-buffered staging, counted
// vmcnt(6) + raw s_barrier per chunk (never drained in-loop).
// ---------------------------------------------------------------------------
__global__ __launch_bounds__(256, 2) void attn_mfma_kernel(
    const float* __restrict__ tr_g, const float* __restrict__ ti_g,
    const __hip_bfloat16* __restrict__ WqT,
    const float* __restrict__ bqr, const float* __restrict__ bqi,
    const __hip_bfloat16* __restrict__ Kh, const __hip_bfloat16* __restrict__ VrT,
    const float* __restrict__ gamma_p, float* __restrict__ out)
{
    __shared__ __align__(16) char smem[73728];
    // Phase 1: As[64][528] @0 (input), Qh[64][528] @33792 (Q-hat).
    // Phase 2: 3 x 24576 chunk buffers @0.
    // Phase 3: Of0[128][65]f32 @0, Of1 @33280, l[2][64] @66560, invl @67072.
    char* As = smem;
    char* Qh = smem + 33792;

    const int b    = blockIdx.x & 7;             // batch -> XCD affinity
    const int n0   = (blockIdx.x >> 3) * 64;
    const int tid  = threadIdx.x;
    const int w    = tid >> 6, lane = tid & 63;
    const int l15  = lane & 15, q8 = lane >> 4;  // 16x16 Q-proj geometry
    const int l31  = lane & 31, hi = lane >> 5;  // 32x32 loop geometry
    const int w01  = w & 1, wprt = w >> 1;       // q-half, chunk parity

    // ---- stage target tile As[n][c] (64 x 256 bf16) ----
    for (int i = tid; i < 64 * 64; i += 256) {
        const int cp = i >> 6, n = i & 63, c = cp * 2;
        const size_t rb = (size_t)(b * NC + c) * NT + n0 + n;
        const unsigned pr = (unsigned short)f2b(tr_g[rb]) |
                            ((unsigned)(unsigned short)f2b(tr_g[rb + NT]) << 16);
        const unsigned pi = (unsigned short)f2b(ti_g[rb]) |
                            ((unsigned)(unsigned short)f2b(ti_g[rb + NT]) << 16);
        *(unsigned*)(As + n * 528 + c * 2)         = pr;
        *(unsigned*)(As + n * 528 + (128 + c) * 2) = pi;
    }
    __syncthreads();

    // ---- cooperative Q-proj: wave w -> cols 64w..64w+63, all 64 rows ----
    {
        f32x4 qacc[4][4];
        #pragma unroll
        for (int rg = 0; rg < 4; ++rg)
            #pragma unroll
            for (int jj = 0; jj < 4; ++jj) {
                qacc[rg][jj][0]=0.f; qacc[rg][jj][1]=0.f;
                qacc[rg][jj][2]=0.f; qacc[rg][jj][3]=0.f;
            }
        #pragma unroll
        for (int t = 0; t < 8; ++t) {
            bf16x8 af[4];
            #pragma unroll
            for (int rg = 0; rg < 4; ++rg)
                af[rg] = *(const bf16x8*)(As + (rg * 16 + l15) * 528 + (t * 32 + q8 * 8) * 2);
            #pragma unroll
            for (int jj = 0; jj < 4; ++jj) {
                const int col = (w * 4 + jj) * 16 + l15;
                const bf16x8 bf = *(const bf16x8*)((const char*)WqT + col * 512 + (t * 32 + q8 * 8) * 2);
                #pragma unroll
                for (int rg = 0; rg < 4; ++rg)
                    qacc[rg][jj] = MFMA16(af[rg], bf, qacc[rg][jj]);
            }
        }
        const float inv_s = 0.12751744f;         // log2(e) / sqrt(128)
        #pragma unroll
        for (int jj = 0; jj < 4; ++jj) {
            const int col  = (w * 4 + jj) * 16 + l15;
            const float bv = (col < 128) ? bqr[col] : bqi[col - 128];
            #pragma unroll
            for (int rg = 0; rg < 4; ++rg)
                #pragma unroll
                for (int r = 0; r < 4; ++r)
                    *(__hip_bfloat16*)(Qh + (rg * 16 + q8 * 4 + r) * 528 + col * 2) =
                        __float2bfloat16((qacc[rg][jj][r] + bv) * inv_s);
        }
    }
    __syncthreads();

    // ---- extract qf[16]: B-frags of my 32 q-rows (col = l31 = q) ----
    bf16x8 qf[16];
    #pragma unroll
    for (int t = 0; t < 16; ++t)
        qf[t] = *(const bf16x8*)(Qh + (w01 * 32 + l31) * 528 + t * 32 + hi * 16);
    __syncthreads();        // Qh/As dead; buffer region free

    const char* Kbase = (const char*)Kh + ((size_t)(b * NS) << 9);
    const char* Vbase = (const char*)VrT + (size_t)b * NC * NS * 2;
    char* bA = smem;
    char* bB = smem + 24576;
    char* bC = smem + 49152;

    stage_chunk(Kbase, Vbase, bA, 0, w, lane);
    stage_chunk(Kbase, Vbase, bB, 1, w, lane);

    f32x16 oacc[4];
    #pragma unroll
    for (int jd = 0; jd < 4; ++jd)
        #pragma unroll
        for (int r = 0; r < 16; ++r) oacc[jd][r] = 0.f;
    f32x16 lacc;
    #pragma unroll
    for (int r = 0; r < 16; ++r) lacc[r] = 0.f;

    bf16x8 onesf;                    // all-ones B: D[q][*] = row sums of P
    #pragma unroll
    for (int e = 0; e < 8; ++e) onesf[e] = (short)0x3F80;

    #pragma unroll 1
    for (int ch = 0; ch < 32; ++ch) {
        asm volatile("s_waitcnt vmcnt(6)" ::: "memory");
        __builtin_amdgcn_s_barrier();    // raw: no vmcnt(0) drain

        const int sch = (ch + 2 < 32) ? ch + 2 : 31;
        stage_chunk(Kbase, Vbase, bC, sch, w, lane);

        if ((ch & 1) == wprt) {
            // ---- QK^T: S = mfma32(K, Q); lane: col = q, regs = k-rows ----
            f32x16 s;
            #pragma unroll
            for (int r = 0; r < 16; ++r) s[r] = 0.f;
            #pragma unroll
            for (int t = 0; t < 16; ++t) {
                const bf16x8 kf = *(const bf16x8*)(
                    bA + l31 * 512 + (((2 * t + hi) ^ (l31 & 7)) << 4));
                s = MFMA32(kf, qf[t], s);
            }
            // ---- p = 2^S' ----
            #pragma unroll
            for (int r = 0; r < 16; ++r) s[r] = exp2f(s[r]);

            // ---- assemble PV A-frags per 16-k window; PV + denominator ----
            #pragma unroll
            for (int t2 = 0; t2 < 2; ++t2) {
                const int o = t2 * 8;
                const unsigned x0 = pk2(s[o + 0], s[o + 1]);
                const unsigned x1 = pk2(s[o + 2], s[o + 3]);
                const unsigned y0 = pk2(s[o + 4], s[o + 5]);
                const unsigned y1 = pk2(s[o + 6], s[o + 7]);
                const unsigned xs0 = __shfl_xor(x0, 32);
                const unsigned xs1 = __shfl_xor(x1, 32);
                const unsigned ys0 = __shfl_xor(y0, 32);
                const unsigned ys1 = __shfl_xor(y1, 32);
                union { unsigned u[4]; bf16x8 v; } pu;
                pu.u[0] = hi ? ys0 : x0;     // elems k_rel = 8hi+0,1
                pu.u[1] = hi ? ys1 : x1;     // 8hi+2,3
                pu.u[2] = hi ? y0  : xs0;    // 8hi+4,5
                pu.u[3] = hi ? y1  : xs1;    // 8hi+6,7
                const bf16x8 paf = pu.v;
                lacc = MFMA32(paf, onesf, lacc);
                #pragma unroll
                for (int jd = 0; jd < 4; ++jd) {
                    const bf16x8 vf = *(const bf16x8*)(
                        bA + 16384 + (jd * 32 + l31) * 64 +
                        (((2 * t2 + hi) ^ (l31 & 3)) << 4));
                    oacc[jd] = MFMA32(paf, vf, oacc[jd]);
                }
            }
        }

        char* t0 = bA; bA = bB; bB = bC; bC = t0;   // rotate buffers
    }

    // ---- epilogue: merge parity partials through LDS ----
    __syncthreads();                         // drains staging; buffers dead
    float* Ofp = (float*)(smem + wprt * 33280);   // my parity's partial
    #pragma unroll
    for (int jd = 0; jd < 4; ++jd)
        #pragma unroll
        for (int r = 0; r < 16; ++r) {
            const int m = w01 * 32 + (r & 3) + 8 * (r >> 2) + 4 * hi;
            Ofp[(jd * 32 + l31) * 65 + m] = oacc[jd][r];
        }
    float* lf = (float*)(smem + 66560);
    if (l31 == 0) {
        #pragma unroll
        for (int r = 0; r < 16; ++r) {
            const int m = w01 * 32 + (r & 3) + 8 * (r >> 2) + 4 * hi;
            lf[wprt * 64 + m] = lacc[r];
        }
    }
    __syncthreads();
    float* invl = (float*)(smem + 67072);
    if (tid < 64)
        invl[tid] = gamma_p[0] / fmaxf(lf[tid] + lf[64 + tid], 1e-30f);
    __syncthreads();

    const float* Of0 = (const float*)smem;
    const float* Of1 = (const float*)(smem + 33280);
    float* ob = out + (size_t)b * NC * NT + n0;
    for (int i = tid; i < 128 * 64; i += 256) {
        const int d = i >> 6, m = i & 63;
        ob[(size_t)d * NT + m] = (Of0[d * 65 + m] + Of1[d * 65 + m]) * invl[m];
    }
}

// ---------------------------------------------------------------------------
extern "C" void kernel_launch(void* const* d_in, const int* in_sizes, int n_in,
                              void* d_out, int out_size, void* d_ws, size_t ws_size,
                              hipStream_t stream)
{
    const float* target_r = (const float*)d_in[0];
    const float* target_i = (const float*)d_in[1];
    const float* source_r = (const float*)d_in[2];
    const float* source_i = (const float*)d_in[3];
    const float* Wq_r = (const float*)d_in[4];
    const float* Wq_i = (const float*)d_in[5];
    const float* bq_r = (const float*)d_in[6];
    const float* bq_i = (const float*)d_in[7];
    const float* Wk_r = (const float*)d_in[8];
    const float* Wk_i = (const float*)d_in[9];
    const float* bk_r = (const float*)d_in[10];
    const float* bk_i = (const float*)d_in[11];
    const float* Wv_r = (const float*)d_in[12];
    const float* Wv_i = (const float*)d_in[13];
    const float* bv_r = (const float*)d_in[14];
    const float* bv_i = (const float*)d_in[15];
    const float* gamma = (const float*)d_in[16];

    // workspace carve (bytes) — total 6.62 MB
    char* ws = (char*)d_ws;
    __hip_bfloat16* Kh  = (__hip_bfloat16*)(ws);                    // 4,194,304
    __hip_bfloat16* VrT = (__hip_bfloat16*)(ws + 4194304);          // 2,097,152
    __hip_bfloat16* WqT = (__hip_bfloat16*)(ws + 6291456);          //   131,072
    __hip_bfloat16* WkT = (__hip_bfloat16*)(ws + 6422528);          //   131,072
    __hip_bfloat16* WvT = (__hip_bfloat16*)(ws + 6553600);          //    65,536

    pack_w_kernel<<<640, 256, 0, stream>>>(Wq_r, Wq_i, Wk_r, Wk_i, Wv_r, Wv_i,
                                           WqT, WkT, WvT);

    projKV_kernel<<<NB * (NS / 16), 256, 0, stream>>>(
        source_r, source_i, WkT, WvT, bk_r, bk_i, bv_r, Kh, VrT);

    attn_mfma_kernel<<<NB * (NT / 64), 256, 0, stream>>>(
        target_r, target_i, WqT, bq_r, bq_i, Kh, VrT, gamma, (float*)d_out);
}